// Round 9
// baseline (168.548 us; speedup 1.0000x reference)
//
#include <hip/hip_runtime.h>
#include <stdint.h>
#include <stddef.h>

// RadialCTC: cosine logits (norm_scale=32) -> log_softmax -> CTC(sum).
// Strategy: never materialize the (16384 x 1296) logits. GEMM (f16 MFMA)
// computes per-row sum(exp(logit)) fused in the epilogue; label log-probs via
// small f16 MFMA gather-GEMM; CTC alpha recursion one wave per sample.
// R9: linear f64 + pow2 renorm ctc. R11: XOR channel-slot LDS swizzle (gemm).
// R12: dispatch-count collapse: NO CHANGE. R14: log2(sumexp) factored out.
// R15 FAILED: agent-scope acquire spins -> buffer_inv storms killed L2.
// R16/R17: gather+ctc fused per-sample block; mega 62-67us.
// R18 (154.2): fused 2-step chain + renorm/8 + setprio: mega 54.9.
// R19 (153.2): renorm/16+setprio3 NULL; XCD remap cut FETCH 33.6->22.3MB but
//   duration flat -> gemm not the pole; chain micro-opts exhausted. Chain
//   effective ~220cyc/step (contended dependent latency), ~48us of mega.
// R20 (this round): HALVE the serial chain - fwd/bwd split. Answer =
//   (e_{Ln-1}+e_{Ln-2})^T A_{Tin-1}..A_256 alpha_255: wave0 runs forward
//   t=1..255; wave1 runs the BACKWARD row recursion v^T <- v^T A_t from
//   t=Tin-1 down to 256 (banded, shifts down, 2-step-fused with off-chain
//   coefficients mirroring forward); combine = cross-wave f64 dot via LDS.
//   Invalid lanes masked via p=0 so garbage can't flow down into valid
//   states. Gather: 2 waves produce chunks {0,3} then {1,2} so both chains
//   start after one barrier; 3 matched barriers. Gemm/prep/final unchanged.

typedef _Float16 f16;
typedef _Float16 f16x8 __attribute__((ext_vector_type(8)));
typedef float f32x4 __attribute__((ext_vector_type(4)));
typedef __attribute__((address_space(1))) void* as1_void_ptr;
typedef __attribute__((address_space(3))) void* as3_void_ptr;

#define TT 512
#define NN 32
#define CC 1296
#define DD 512
#define SS 30
#define CP 1408   // C padded to 11*128 for GEMM tiling (pad rows are zero)
#define LL 61     // 2*S+1 CTC states
#define NORM_SCALE 32.0f
#define LOG2E 1.4426950408889634f
#define LN2   0.6931471805599453f

#define PREP_WBLK (CP / 16)            // 88 c-tiles of 16 (covers pad -> zeros)
#define PREP_ZBLK 16                   // 16 blocks zero sumexp
#define PREP_FBLK (TT * NN / 4)        // 4096 fnorm blocks (4 rows each)

#define GEMM_BLK ((TT * NN / 128) * (CP / 128))   // 128*11 = 1408
#define MEGA_GC  NN                                // 32 gather+ctc blocks
#define MEGA_BLK (MEGA_GC + GEMM_BLK)              // 1440

__device__ __forceinline__ float fexp2(float x) { return __builtin_amdgcn_exp2f(x); }
__device__ __forceinline__ float flog2(float x) { return __builtin_amdgcn_logf(x); }

// whole-wave shift-right-by-1 (lane s <- lane s-1; lane 0 gets 0): ctrl 0x138.
__device__ __forceinline__ double dpp_sr1_zero64(double x) {
    long long b = __double_as_longlong(x);
    int lo = (int)(b & 0xFFFFFFFFLL);
    int hi = (int)(b >> 32);
    int lo2 = __builtin_amdgcn_update_dpp(0, lo, 0x138, 0xF, 0xF, false);
    int hi2 = __builtin_amdgcn_update_dpp(0, hi, 0x138, 0xF, 0xF, false);
    return __longlong_as_double(((long long)hi2 << 32) |
                                (unsigned long long)(unsigned int)lo2);
}
// whole-wave shift-left-by-1 (lane s <- lane s+1; lane 63 gets 0): ctrl 0x130.
__device__ __forceinline__ double dpp_sl1_zero64(double x) {
    long long b = __double_as_longlong(x);
    int lo = (int)(b & 0xFFFFFFFFLL);
    int hi = (int)(b >> 32);
    int lo2 = __builtin_amdgcn_update_dpp(0, lo, 0x130, 0xF, 0xF, false);
    int hi2 = __builtin_amdgcn_update_dpp(0, hi, 0x130, 0xF, 0xF, false);
    return __longlong_as_double(((long long)hi2 << 32) |
                                (unsigned long long)(unsigned int)lo2);
}
__device__ __forceinline__ float dpp_sl1_zero32(float x) {
    int r = __builtin_amdgcn_update_dpp(0, __float_as_int(x), 0x130, 0xF, 0xF, false);
    return __int_as_float(r);
}
// one level of DPP row-shr int max (identity 0; operands are >=0 hi-words)
template <int CTRL>
__device__ __forceinline__ int dpp_imax_level(int m) {
    int t = __builtin_amdgcn_update_dpp(0, m, CTRL, 0xF, 0xF, false);
    return m > t ? m : t;
}
// exact pow2 renorm of a nonneg f64 wave vector; accumulates exponent in Mi.
__device__ __forceinline__ void renorm_d(double& x, int& Mi) {
    int h = (int)(__double_as_longlong(x) >> 32);   // x>=0: hi-word monotone
    h = dpp_imax_level<0x111>(h);
    h = dpp_imax_level<0x112>(h);
    h = dpp_imax_level<0x114>(h);
    h = dpp_imax_level<0x118>(h);        // row max in lanes 15/31/47/63
    int r0 = __builtin_amdgcn_readlane(h, 15);
    int r1 = __builtin_amdgcn_readlane(h, 31);
    int r2 = __builtin_amdgcn_readlane(h, 47);
    int r3 = __builtin_amdgcn_readlane(h, 63);
    int mx = max(max(r0, r1), max(r2, r3));
    int e11 = mx >> 20;                  // biased 11-bit exponent
    double scale = __longlong_as_double((long long)(2046 - e11) << 52);
    x *= scale;
    Mi += e11 - 1023;
}

// ---- fused prep: W column-norm + transpose to f16 (atomic-free, per-block
//      column ownership), feats row-normalize -> f16, sumexp zeroing. ----
__global__ __launch_bounds__(256) void prep_kernel(const float* __restrict__ W,
                                                   const float* __restrict__ feats,
                                                   f16* __restrict__ wt,
                                                   f16* __restrict__ fn,
                                                   float* __restrict__ sumexp) {
    int bx = blockIdx.x, tid = threadIdx.x;
    if (bx < PREP_WBLK) {
        __shared__ float red[256];
        __shared__ float rqs[16];
        int c0 = bx * 16;
        int cl = tid & 15, dg = tid >> 4;
        int c = c0 + cl;
        float ss = 0.f;
        if (c < CC) {
            for (int d = dg; d < DD; d += 16) {
                float v = W[(size_t)d * CC + c];
                ss += v * v;
            }
        }
        red[tid] = ss;
        __syncthreads();
        if (tid < 16) {
            float s2 = 0.f;
            #pragma unroll
            for (int k = 0; k < 16; ++k) s2 += red[tid + 16 * k];
            rqs[tid] = rsqrtf(s2);
        }
        __syncthreads();
        int c_loc = tid >> 4, dl = tid & 15;
        int cc = c0 + c_loc;
        float rq = rqs[c_loc];
        #pragma unroll 4
        for (int it = 0; it < 32; ++it) {
            int d = dl + it * 16;
            float v = (cc < CC) ? W[(size_t)d * CC + cc] * rq : 0.f;
            wt[(size_t)cc * DD + d] = (f16)v;
        }
    } else if (bx < PREP_WBLK + PREP_ZBLK) {
        int zb = bx - PREP_WBLK;
        float4 z = {0.f, 0.f, 0.f, 0.f};
        ((float4*)sumexp)[zb * 256 + tid] = z;   // 16*256*16B = 64KB
    } else {
        int fb = bx - PREP_WBLK - PREP_ZBLK;
        int wv = (fb * 256 + tid) >> 6;  // row id, 0..16383
        int lane = tid & 63;
        const float4* src = (const float4*)(feats + (size_t)wv * DD) + lane * 2;
        float4 a = src[0], b = src[1];
        float ss = a.x*a.x + a.y*a.y + a.z*a.z + a.w*a.w
                 + b.x*b.x + b.y*b.y + b.z*b.z + b.w*b.w;
        #pragma unroll
        for (int off = 32; off; off >>= 1) ss += __shfl_xor(ss, off);
        float r = rsqrtf(ss);
        f16x8 o;
        o[0]=(f16)(a.x*r); o[1]=(f16)(a.y*r); o[2]=(f16)(a.z*r); o[3]=(f16)(a.w*r);
        o[4]=(f16)(b.x*r); o[5]=(f16)(b.y*r); o[6]=(f16)(b.z*r); o[7]=(f16)(b.w*r);
        *(f16x8*)(fn + (size_t)wv * DD + lane * 8) = o;
    }
}

// ---- one gather pass: NT 16-row t-tiles of chunk c starting at rbase.
//      Register-direct MFMA frags (A row=lane&15, k=(lane>>4)*8). No barriers. ----
template <int NT>
__device__ __forceinline__ void gather_chunk(const f16* __restrict__ pb0,
                                             const f16* __restrict__ pb1,
                                             const f16* __restrict__ A,
                                             float* __restrict__ lp_lab,
                                             int n, int c, int rbase, int lane) {
    int lm = lane & 15, hi = lane >> 4;
    const f16* pa0 = A + ((size_t)(c * 128 + rbase + lm) * NN + n) * DD + hi * 8;
    f32x4 acc[NT][2];
    #pragma unroll
    for (int i = 0; i < NT; ++i) {
        acc[i][0] = (f32x4){0.f, 0.f, 0.f, 0.f};
        acc[i][1] = (f32x4){0.f, 0.f, 0.f, 0.f};
    }
    for (int kb = 0; kb < 16; ++kb) {
        f16x8 bf0 = *(const f16x8*)(pb0 + kb * 32);
        f16x8 bf1 = *(const f16x8*)(pb1 + kb * 32);
        #pragma unroll
        for (int i = 0; i < NT; ++i) {
            f16x8 af = *(const f16x8*)(pa0 + (size_t)(i * 16) * NN * DD + kb * 32);
            acc[i][0] = __builtin_amdgcn_mfma_f32_16x16x32_f16(af, bf0, acc[i][0], 0, 0, 0);
            acc[i][1] = __builtin_amdgcn_mfma_f32_16x16x32_f16(af, bf1, acc[i][1], 0, 0, 0);
        }
    }
    #pragma unroll
    for (int i = 0; i < NT; ++i) {
        #pragma unroll
        for (int jn = 0; jn < 2; ++jn) {
            int jc = jn * 16 + lm;
            if (jc >= 31) continue;
            float4 o;
            o.x = acc[i][jn][0] * (NORM_SCALE * LOG2E);
            o.y = acc[i][jn][1] * (NORM_SCALE * LOG2E);
            o.z = acc[i][jn][2] * (NORM_SCALE * LOG2E);
            o.w = acc[i][jn][3] * (NORM_SCALE * LOG2E);
            *(float4*)&lp_lab[((size_t)n * 31 + jc) * TT
                              + c * 128 + rbase + i * 16 + hi * 4] = o;
        }
    }
}

// ---- mega: blocks 0..31 = {wave0 fwd chain, wave1 bwd chain, waves2-3
//      gather}; blocks 32..1439 = gemm+sumexp (16KB LDS, XOR swizzle,
//      XCD-aware bm grouping). gc barriers: b0 (chunks 0,3), b1 (1,2),
//      b2 (bwd v published to LDS) - all 4 waves hit exactly 3. ----
__global__ __launch_bounds__(256) void mega_kernel(const f16* __restrict__ A,
                                                   const f16* __restrict__ B,
                                                   const int* __restrict__ labels,
                                                   const int* __restrict__ in_lens,
                                                   const int* __restrict__ lab_lens,
                                                   float* __restrict__ sumexp,
                                                   float* __restrict__ lp_lab,
                                                   double* __restrict__ part) {
    __shared__ __align__(16) f16 sm[8192];   // 16 KB (gemm tiles | gc dot buf)
    int bx = blockIdx.x;
    int tid = threadIdx.x;
    int w = tid >> 6, lane = tid & 63;
    int lm = lane & 15, hi = lane >> 4;
    int sw = (lm >> 1) & 3;                // fragment-read channel swizzle

    if (bx >= MEGA_GC) {
        // ================= GEMM section (identical since R19) ===============
        int j = bx - MEGA_GC;
        int x = j & 7, rr = j >> 3;            // XCD-aware: per-XCD bm range
        int bm = x * 16 + (rr & 15);
        int bn = rr >> 4;                      // [0,11)
        int wm = w >> 1, wn = w & 1;           // 2x2 wave grid -> 64x64 per wave
        f32x4 acc[4][4];
        f32x4 zero = {0.f, 0.f, 0.f, 0.f};
        #pragma unroll
        for (int i = 0; i < 4; ++i)
            #pragma unroll
            for (int jj = 0; jj < 4; ++jj) acc[i][jj] = zero;

        for (int kb = 0; kb < 16; ++kb) {      // K=512, BK=32 (one MFMA K-step)
            #pragma unroll
            for (int p = 0; p < 2; ++p) {
                int s = p * 256 + tid;
                int row = s >> 2;
                int ch = (s & 3) ^ ((row >> 1) & 3);   // swizzled source channel
                const f16* ga = A + (size_t)(bm * 128 + row) * DD + kb * 32 + ch * 8;
                const f16* gb = B + (size_t)(bn * 128 + row) * DD + kb * 32 + ch * 8;
                __builtin_amdgcn_global_load_lds((as1_void_ptr)ga,
                    (as3_void_ptr)&sm[(p * 256 + w * 64) * 8], 16, 0, 0);
                __builtin_amdgcn_global_load_lds((as1_void_ptr)gb,
                    (as3_void_ptr)&sm[4096 + (p * 256 + w * 64) * 8], 16, 0, 0);
            }
            __syncthreads();
            f16x8 af[4], bf[4];
            #pragma unroll
            for (int i = 0; i < 4; ++i)
                af[i] = *(const f16x8*)&sm[(wm * 64 + i * 16 + lm) * 32 + (hi ^ sw) * 8];
            #pragma unroll
            for (int jj = 0; jj < 4; ++jj)
                bf[jj] = *(const f16x8*)&sm[4096 + (wn * 64 + jj * 16 + lm) * 32 + (hi ^ sw) * 8];
            #pragma unroll
            for (int i = 0; i < 4; ++i)
                #pragma unroll
                for (int jj = 0; jj < 4; ++jj)
                    acc[i][jj] = __builtin_amdgcn_mfma_f32_16x16x32_f16(af[i], bf[jj], acc[i][jj], 0, 0, 0);
            __syncthreads();
        }
        #pragma unroll
        for (int i = 0; i < 4; ++i) {
            float rs[4] = {0.f, 0.f, 0.f, 0.f};
            #pragma unroll
            for (int jj = 0; jj < 4; ++jj) {
                int c = bn * 128 + wn * 64 + jj * 16 + lm;   // C/D: col = lane&15
                bool ok = (c < CC);
                #pragma unroll
                for (int r = 0; r < 4; ++r)
                    rs[r] += ok ? fexp2(acc[i][jj][r] * (NORM_SCALE * LOG2E)) : 0.f;
            }
            #pragma unroll
            for (int off = 1; off < 16; off <<= 1) {
                #pragma unroll
                for (int r = 0; r < 4; ++r) rs[r] += __shfl_xor(rs[r], off);
            }
            if (lm == 0) {
                int rowb = bm * 128 + wm * 64 + i * 16 + hi * 4;
                #pragma unroll
                for (int r = 0; r < 4; ++r) atomicAdd(&sumexp[rowb + r], rs[r]);
            }
        }
        return;
    }

    // ================= gather + fwd/bwd ctc section (block n = bx) ==========
    int n = bx;
    if (w >= 2) {
        // gather waves: wave2 -> chunks 0,1; wave3 -> chunks 3,2
        __builtin_amdgcn_s_setprio(2);
        int cls0 = (lm == 0) ? 0 : labels[n * SS + lm - 1];       // j = lm
        int cls1 = (lm >= 15) ? 0 : labels[n * SS + lm + 15];     // j = 16+lm
        const f16* pb0 = B + (size_t)cls0 * DD + hi * 8;
        const f16* pb1 = B + (size_t)cls1 * DD + hi * 8;
        int cA = (w == 2) ? 0 : 3;
        int cB = (w == 2) ? 1 : 2;
        gather_chunk<4>(pb0, pb1, A, lp_lab, n, cA, 0, lane);
        gather_chunk<4>(pb0, pb1, A, lp_lab, n, cA, 64, lane);
        __syncthreads();                     // b0: chunks 0,3 published
        gather_chunk<4>(pb0, pb1, A, lp_lab, n, cB, 0, lane);
        gather_chunk<4>(pb0, pb1, A, lp_lab, n, cB, 64, lane);
        __builtin_amdgcn_s_setprio(0);
        __syncthreads();                     // b1: chunks 1,2 published
        __syncthreads();                     // b2 (match chain waves)
        return;
    }

    int s = lane;            // 64 lanes; states 0..60 valid
    bool valid = s < LL;
    int ext = (valid && (s & 1)) ? labels[n * SS + (s >> 1)] : 0;
    int jmap = (valid && (s & 1)) ? ((s >> 1) + 1) : 0;   // state -> class slot
    int Tin = in_lens[n];    // wave-uniform; in [481,512]
    const float* lpr = lp_lab + ((size_t)n * 31 + jmap) * TT;
    double* vb = (double*)sm;                // cross-wave dot buffer

    if (w == 0) {
        // ---------------- forward: alpha over t = 0..255 --------------------
        int ext2 = __shfl_up(ext, 2);
        double skipd = ((s >= 2) && valid && (ext != ext2)) ? 1.0 : 0.0;
        double sk1 = dpp_sr1_zero64(skipd);
        double sk2 = dpp_sr1_zero64(sk1);
        double kk2 = skipd * sk2;
        const float4* g4 = (const float4*)lpr;
        double beta = 0.0;
        int Mif = 0;

        auto stepL = [&](float lp) {
            double P = (double)fexp2(lp);
            double b1 = dpp_sr1_zero64(beta);
            double b2 = dpp_sr1_zero64(b1);
            beta = (beta + b1 + b2 * skipd) * P;
        };
        auto step2 = [&](float lp1, float lp2) {
            double q  = (double)fexp2(lp1);
            double P2 = (double)fexp2(lp2);
            double q1 = dpp_sr1_zero64(q);
            double q2 = dpp_sr1_zero64(q1);
            double c1 = q + q1;
            double c2 = fma(skipd, q + q2, q1);
            double c3 = fma(sk1, q1, skipd * q2);
            double c4 = kk2 * q2;
            double b1 = dpp_sr1_zero64(beta);
            double b2 = dpp_sr1_zero64(b1);
            double b3 = dpp_sr1_zero64(b2);
            double b4 = dpp_sr1_zero64(b3);
            double u = fma(c1, b1, q * beta);
            double v2 = fma(c3, b3, c2 * b2);
            beta = (u + fma(c4, b4, v2)) * P2;
        };

        __builtin_amdgcn_s_setprio(3);
        __syncthreads();                     // b0: chunk 0 ready
        float4 q0 = g4[0];
        beta = (s <= 1) ? (double)fexp2(q0.x) : 0.0;
        stepL(q0.y); stepL(q0.z); stepL(q0.w);   // t = 1..3
        renorm_d(beta, Mif);
        float4 cu = g4[1];
        for (int gi = 1; gi <= 31; ++gi) {       // t = 4..127
            float4 nx = g4[gi < 31 ? gi + 1 : 31];
            step2(cu.x, cu.y); step2(cu.z, cu.w);
            if (gi & 1) renorm_d(beta, Mif);
            cu = nx;
        }
        __syncthreads();                     // b1: chunk 1 ready
        cu = g4[32];
        for (int gi = 32; gi <= 63; ++gi) {      // t = 128..255
            float4 nx = g4[gi < 63 ? gi + 1 : 63];
            step2(cu.x, cu.y); step2(cu.z, cu.w);
            if (gi & 1) renorm_d(beta, Mif);
            cu = nx;
        }
        renorm_d(beta, Mif);
        __syncthreads();                     // b2: bwd vector published
        __builtin_amdgcn_s_setprio(0);
        double pr = beta * vb[s];            // v[s>=LL] == 0: garbage excluded
        #pragma unroll
        for (int off = 32; off; off >>= 1) pr += __shfl_xor(pr, off);
        if (s == 0) {
            long long bb = __double_as_longlong(pr);
            int e = (int)(bb >> 52) - 1023;
            double mant = __longlong_as_double((bb & 0xFFFFFFFFFFFFFLL) | (1023LL << 52));
            part[n] = (double)flog2((float)mant) + (double)(e + Mif) + vb[64];
        }
        return;
    }

    // ---------------- backward: v^T <- v^T A_t, t = Tin-1 .. 256 ------------
    {
        float maskf = valid ? 1.f : 0.f;     // p=0 outside states: no garbage
        int extd1 = __shfl_down(ext, 1);
        int extd2 = __shfl_down(ext, 2);
        int extd3 = __shfl_down(ext, 3);
        int extd4 = __shfl_down(ext, 4);
        double k2d = ((s + 2) < LL && extd2 != ext)   ? 1.0 : 0.0;  // k[s+2]
        double k3d = ((s + 3) < LL && extd3 != extd1) ? 1.0 : 0.0;  // k[s+3]
        double k4d = ((s + 4) < LL && extd4 != extd2) ? 1.0 : 0.0;  // k[s+4]
        int Ln = 2 * lab_lens[n] + 1;
        double v = (s == Ln - 1 || s == Ln - 2) ? 1.0 : 0.0;
        int Mib = 0;

        // v'' = c0*v + c1*v[s+1] + c2*v[s+2] + c3*v[s+3] + c4*v[s+4]
        // (A_t then A_{t-1}; p=2^lp_t, r=2^lp_{t-1}; derived in R20 notes)
        auto step2b = [&](float lph, float lpl) {
            float p  = maskf * fexp2(lph);
            float rr = maskf * fexp2(lpl);
            float p1 = dpp_sl1_zero32(p);
            float p2 = dpp_sl1_zero32(p1);
            float p3 = dpp_sl1_zero32(p2);
            float p4 = dpp_sl1_zero32(p3);
            float r1 = dpp_sl1_zero32(rr);
            float r2 = dpp_sl1_zero32(r1);
            double rd = (double)rr, rd1 = (double)r1, rd2 = (double)r2;
            double c0 = (double)p * rd;
            double c1 = (double)p1 * (rd + rd1);
            double c2 = (double)p2 * fma(k2d, rd + rd2, rd1);
            double c3 = (double)p3 * fma(k3d, rd1, k2d * rd2);
            double c4 = (double)p4 * (k2d * rd2) * k4d;
            double v1 = dpp_sl1_zero64(v);
            double v2 = dpp_sl1_zero64(v1);
            double v3 = dpp_sl1_zero64(v2);
            double v4 = dpp_sl1_zero64(v3);
            double u  = fma(c1, v1, c0 * v);
            double t2 = fma(c3, v3, c2 * v2);
            v = u + fma(c4, v4, t2);
        };
        auto step1b = [&](float lph) {       // v' = u + u[s+1] + k[s+2]u[s+2]
            float p = maskf * fexp2(lph);
            double u  = (double)p * v;
            double u1 = dpp_sl1_zero64(u);
            double u2 = dpp_sl1_zero64(u1);
            v = u + u1 + k2d * u2;
        };

        __builtin_amdgcn_s_setprio(3);
        __syncthreads();                     // b0: chunk 3 (t>=384) ready
        int tc = Tin - 1;
        float h0 = lpr[tc], l0 = lpr[tc - 1];
        int rnc = 0;
        while (tc >= 385) {                  // phase A: down to t=384
            int tn = tc - 2;
            float h1 = (tn >= 384) ? lpr[tn] : 0.f;       // stay in chunk 3
            float l1 = (tn >= 385) ? lpr[tn - 1] : 0.f;
            step2b(h0, l0);
            if (((++rnc) & 3) == 0) renorm_d(v, Mib);
            tc = tn; h0 = h1; l0 = l1;
        }
        if (tc == 384) { step1b(h0); tc = 383; }
        renorm_d(v, Mib);
        __syncthreads();                     // b1: chunk 2 (t in [256,384)) ready
        tc = 383;
        h0 = lpr[tc]; l0 = lpr[tc - 1];
        rnc = 0;
        while (tc >= 257) {                  // phase B: down to t=256
            int tn = tc - 2;
            float h1 = (tn >= 257) ? lpr[tn] : 0.f;
            float l1 = (tn >= 257) ? lpr[tn - 1] : 0.f;
            step2b(h0, l0);
            if (((++rnc) & 3) == 0) renorm_d(v, Mib);
            tc = tn; h0 = h1; l0 = l1;
        }
        renorm_d(v, Mib);
        vb[s] = v;
        if (s == 0) vb[64] = (double)Mib;
        __builtin_amdgcn_s_setprio(0);
        __syncthreads();                     // b2: publish v + Mi_b
        return;
    }
}

// ---- final: Msum per n (f64, fixed order) + nll + deterministic sum ----
__global__ __launch_bounds__(1024) void final_kernel(const float* __restrict__ sumexp,
                                                     const int* __restrict__ in_lens,
                                                     const double* __restrict__ part,
                                                     float* __restrict__ out) {
    int tid = threadIdx.x;
    int v = tid >> 6, lane = tid & 63;     // 16 waves, 2 samples each
    __shared__ float nl[NN];
    #pragma unroll
    for (int k = 0; k < 2; ++k) {
        int n = v * 2 + k;
        int Tin = in_lens[n];
        double ms = 0.0;
        for (int t = lane; t < Tin; t += 64)
            ms += (double)flog2(sumexp[(size_t)t * NN + n]);
        #pragma unroll
        for (int off = 32; off; off >>= 1) ms += __shfl_xor(ms, off);
        if (lane == 0) nl[n] = (float)(-(part[n] - ms) * LN2);
    }
    __syncthreads();
    if (tid == 0) {
        float t = 0.f;
        for (int i = 0; i < NN; ++i) t += nl[i];
        out[0] = t;
    }
}

extern "C" void kernel_launch(void* const* d_in, const int* in_sizes, int n_in,
                              void* d_out, int out_size, void* d_ws, size_t ws_size,
                              hipStream_t stream) {
    const float* feats        = (const float*)d_in[0];
    const float* W            = (const float*)d_in[1];
    const int*   labeling     = (const int*)d_in[2];
    const int*   logit_lgts   = (const int*)d_in[3];
    const int*   labeling_lgts= (const int*)d_in[4];
    float* out = (float*)d_out;
    char* ws = (char*)d_ws;

    size_t off = 0;
    f16*   wt     = (f16*)(ws + off);   off += (size_t)CP * DD * 2;        // 1.44 MB
    f16*   fn     = (f16*)(ws + off);   off += (size_t)TT * NN * DD * 2;   // 16.8 MB
    float* sumexp = (float*)(ws + off); off += (size_t)TT * NN * 4;        // 64 KB
    float* lp_lab = (float*)(ws + off); off += (size_t)NN * 31 * TT * 4;   // 2.0 MB
    double* part  = (double*)(ws + off); off += NN * 8;

    prep_kernel<<<PREP_WBLK + PREP_ZBLK + PREP_FBLK, 256, 0, stream>>>(
        W, feats, wt, fn, sumexp);
    mega_kernel<<<MEGA_BLK, 256, 0, stream>>>(fn, wt, labeling, logit_lgts,
                                              labeling_lgts, sumexp, lp_lab, part);
    final_kernel<<<1, 1024, 0, stream>>>(sumexp, logit_lgts, part, out);

    (void)in_sizes; (void)n_in; (void)out_size; (void)ws_size;
}

// Round 10
// 162.454 us; speedup vs baseline: 1.0375x; 1.0375x over previous
//
#include <hip/hip_runtime.h>
#include <stdint.h>
#include <stddef.h>

// RadialCTC: cosine logits (norm_scale=32) -> log_softmax -> CTC(sum).
// Strategy: never materialize the (16384 x 1296) logits. GEMM (f16 MFMA)
// computes per-row sum(exp(logit)) fused in the epilogue; label log-probs via
// small f16 MFMA gather-GEMM; CTC alpha recursion one wave per sample.
// R9: linear f64 + pow2 renorm ctc. R11: XOR channel-slot LDS swizzle (gemm).
// R14: log2(sumexp) factored out (Msum). R15 FAILED: acquire-spin L2 storms.
// R16/R17: gather+ctc fused per-sample block (no cross-block sync).
// R18 (154.2): fused 2-step chain + renorm/8 + setprio: mega 54.9.
// R19 (153.2): XCD remap cut FETCH 33.6->22.3MB (mechanism worked), duration
//   flat; chain micro-opts null. mega = chain-bound ~54, VGPR 76.
// R20 (168.5): fwd/bwd chain split VERIFIED (absmax 0.0) but VGPR 76->120
//   (fat 2-wave NT=4 gather + bwd prefetch) -> gemm occupancy 6->4 waves/SIMD
//   -> mega 70. LESSON: sectioned mega-kernel = one register budget; the
//   weakest path's VGPR appetite throttles the hottest path.
// R21 (this round): R20's verified chain split + R19's register discipline.
//   320-thread blocks (5 waves): w0 fwd (t=1..255), w1 bwd (t=Tin-1..256,
//   R20 code verbatim), w2-4 = R19's lean gather (NT=3/3/2, runtime-chunk
//   loop), chunk order {0,3} b0 {1,2} b1 b2. Both chains run concurrently in
//   the two inter-barrier intervals. Gemm: waves0-3 identical to R19; wave4
//   matches the 32 barriers. Target VGPR <= ~88.

typedef _Float16 f16;
typedef _Float16 f16x8 __attribute__((ext_vector_type(8)));
typedef float f32x4 __attribute__((ext_vector_type(4)));
typedef __attribute__((address_space(1))) void* as1_void_ptr;
typedef __attribute__((address_space(3))) void* as3_void_ptr;

#define TT 512
#define NN 32
#define CC 1296
#define DD 512
#define SS 30
#define CP 1408   // C padded to 11*128 for GEMM tiling (pad rows are zero)
#define LL 61     // 2*S+1 CTC states
#define NORM_SCALE 32.0f
#define LOG2E 1.4426950408889634f
#define LN2   0.6931471805599453f

#define PREP_WBLK (CP / 16)            // 88 c-tiles of 16 (covers pad -> zeros)
#define PREP_ZBLK 16                   // 16 blocks zero sumexp
#define PREP_FBLK (TT * NN / 4)        // 4096 fnorm blocks (4 rows each)

#define GEMM_BLK ((TT * NN / 128) * (CP / 128))   // 128*11 = 1408
#define MEGA_GC  NN                                // 32 gather+ctc blocks
#define MEGA_BLK (MEGA_GC + GEMM_BLK)              // 1440

__device__ __forceinline__ float fexp2(float x) { return __builtin_amdgcn_exp2f(x); }
__device__ __forceinline__ float flog2(float x) { return __builtin_amdgcn_logf(x); }

// whole-wave shift-right-by-1 (lane s <- lane s-1; lane 0 gets 0): ctrl 0x138.
__device__ __forceinline__ double dpp_sr1_zero64(double x) {
    long long b = __double_as_longlong(x);
    int lo = (int)(b & 0xFFFFFFFFLL);
    int hi = (int)(b >> 32);
    int lo2 = __builtin_amdgcn_update_dpp(0, lo, 0x138, 0xF, 0xF, false);
    int hi2 = __builtin_amdgcn_update_dpp(0, hi, 0x138, 0xF, 0xF, false);
    return __longlong_as_double(((long long)hi2 << 32) |
                                (unsigned long long)(unsigned int)lo2);
}
// whole-wave shift-left-by-1 (lane s <- lane s+1; lane 63 gets 0): ctrl 0x130.
__device__ __forceinline__ double dpp_sl1_zero64(double x) {
    long long b = __double_as_longlong(x);
    int lo = (int)(b & 0xFFFFFFFFLL);
    int hi = (int)(b >> 32);
    int lo2 = __builtin_amdgcn_update_dpp(0, lo, 0x130, 0xF, 0xF, false);
    int hi2 = __builtin_amdgcn_update_dpp(0, hi, 0x130, 0xF, 0xF, false);
    return __longlong_as_double(((long long)hi2 << 32) |
                                (unsigned long long)(unsigned int)lo2);
}
__device__ __forceinline__ float dpp_sl1_zero32(float x) {
    int r = __builtin_amdgcn_update_dpp(0, __float_as_int(x), 0x130, 0xF, 0xF, false);
    return __int_as_float(r);
}
// one level of DPP row-shr int max (identity 0; operands are >=0 hi-words)
template <int CTRL>
__device__ __forceinline__ int dpp_imax_level(int m) {
    int t = __builtin_amdgcn_update_dpp(0, m, CTRL, 0xF, 0xF, false);
    return m > t ? m : t;
}
// exact pow2 renorm of a nonneg f64 wave vector; accumulates exponent in Mi.
__device__ __forceinline__ void renorm_d(double& x, int& Mi) {
    int h = (int)(__double_as_longlong(x) >> 32);   // x>=0: hi-word monotone
    h = dpp_imax_level<0x111>(h);
    h = dpp_imax_level<0x112>(h);
    h = dpp_imax_level<0x114>(h);
    h = dpp_imax_level<0x118>(h);        // row max in lanes 15/31/47/63
    int r0 = __builtin_amdgcn_readlane(h, 15);
    int r1 = __builtin_amdgcn_readlane(h, 31);
    int r2 = __builtin_amdgcn_readlane(h, 47);
    int r3 = __builtin_amdgcn_readlane(h, 63);
    int mx = max(max(r0, r1), max(r2, r3));
    int e11 = mx >> 20;                  // biased 11-bit exponent
    double scale = __longlong_as_double((long long)(2046 - e11) << 52);
    x *= scale;
    Mi += e11 - 1023;
}

// ---- fused prep: W column-norm + transpose to f16 (atomic-free, per-block
//      column ownership), feats row-normalize -> f16, sumexp zeroing. ----
__global__ __launch_bounds__(256) void prep_kernel(const float* __restrict__ W,
                                                   const float* __restrict__ feats,
                                                   f16* __restrict__ wt,
                                                   f16* __restrict__ fn,
                                                   float* __restrict__ sumexp) {
    int bx = blockIdx.x, tid = threadIdx.x;
    if (bx < PREP_WBLK) {
        __shared__ float red[256];
        __shared__ float rqs[16];
        int c0 = bx * 16;
        int cl = tid & 15, dg = tid >> 4;
        int c = c0 + cl;
        float ss = 0.f;
        if (c < CC) {
            for (int d = dg; d < DD; d += 16) {
                float v = W[(size_t)d * CC + c];
                ss += v * v;
            }
        }
        red[tid] = ss;
        __syncthreads();
        if (tid < 16) {
            float s2 = 0.f;
            #pragma unroll
            for (int k = 0; k < 16; ++k) s2 += red[tid + 16 * k];
            rqs[tid] = rsqrtf(s2);
        }
        __syncthreads();
        int c_loc = tid >> 4, dl = tid & 15;
        int cc = c0 + c_loc;
        float rq = rqs[c_loc];
        #pragma unroll 4
        for (int it = 0; it < 32; ++it) {
            int d = dl + it * 16;
            float v = (cc < CC) ? W[(size_t)d * CC + cc] * rq : 0.f;
            wt[(size_t)cc * DD + d] = (f16)v;
        }
    } else if (bx < PREP_WBLK + PREP_ZBLK) {
        int zb = bx - PREP_WBLK;
        float4 z = {0.f, 0.f, 0.f, 0.f};
        ((float4*)sumexp)[zb * 256 + tid] = z;   // 16*256*16B = 64KB
    } else {
        int fb = bx - PREP_WBLK - PREP_ZBLK;
        int wv = (fb * 256 + tid) >> 6;  // row id, 0..16383
        int lane = tid & 63;
        const float4* src = (const float4*)(feats + (size_t)wv * DD) + lane * 2;
        float4 a = src[0], b = src[1];
        float ss = a.x*a.x + a.y*a.y + a.z*a.z + a.w*a.w
                 + b.x*b.x + b.y*b.y + b.z*b.z + b.w*b.w;
        #pragma unroll
        for (int off = 32; off; off >>= 1) ss += __shfl_xor(ss, off);
        float r = rsqrtf(ss);
        f16x8 o;
        o[0]=(f16)(a.x*r); o[1]=(f16)(a.y*r); o[2]=(f16)(a.z*r); o[3]=(f16)(a.w*r);
        o[4]=(f16)(b.x*r); o[5]=(f16)(b.y*r); o[6]=(f16)(b.z*r); o[7]=(f16)(b.w*r);
        *(f16x8*)(fn + (size_t)wv * DD + lane * 8) = o;
    }
}

// ---- one gather pass: NT 16-row t-tiles of chunk c starting at rbase.
//      Register-direct MFMA frags (A row=lane&15, k=(lane>>4)*8). Runtime c
//      (single inlined body -> lean registers). No barriers inside. ----
template <int NT>
__device__ __forceinline__ void gather_chunk(const f16* __restrict__ pb0,
                                             const f16* __restrict__ pb1,
                                             const f16* __restrict__ A,
                                             float* __restrict__ lp_lab,
                                             int n, int c, int rbase, int lane) {
    int lm = lane & 15, hi = lane >> 4;
    const f16* pa0 = A + ((size_t)(c * 128 + rbase + lm) * NN + n) * DD + hi * 8;
    f32x4 acc[NT][2];
    #pragma unroll
    for (int i = 0; i < NT; ++i) {
        acc[i][0] = (f32x4){0.f, 0.f, 0.f, 0.f};
        acc[i][1] = (f32x4){0.f, 0.f, 0.f, 0.f};
    }
    for (int kb = 0; kb < 16; ++kb) {
        f16x8 bf0 = *(const f16x8*)(pb0 + kb * 32);
        f16x8 bf1 = *(const f16x8*)(pb1 + kb * 32);
        #pragma unroll
        for (int i = 0; i < NT; ++i) {
            f16x8 af = *(const f16x8*)(pa0 + (size_t)(i * 16) * NN * DD + kb * 32);
            acc[i][0] = __builtin_amdgcn_mfma_f32_16x16x32_f16(af, bf0, acc[i][0], 0, 0, 0);
            acc[i][1] = __builtin_amdgcn_mfma_f32_16x16x32_f16(af, bf1, acc[i][1], 0, 0, 0);
        }
    }
    #pragma unroll
    for (int i = 0; i < NT; ++i) {
        #pragma unroll
        for (int jn = 0; jn < 2; ++jn) {
            int jc = jn * 16 + lm;
            if (jc >= 31) continue;
            float4 o;
            o.x = acc[i][jn][0] * (NORM_SCALE * LOG2E);
            o.y = acc[i][jn][1] * (NORM_SCALE * LOG2E);
            o.z = acc[i][jn][2] * (NORM_SCALE * LOG2E);
            o.w = acc[i][jn][3] * (NORM_SCALE * LOG2E);
            *(float4*)&lp_lab[((size_t)n * 31 + jc) * TT
                              + c * 128 + rbase + i * 16 + hi * 4] = o;
        }
    }
}

template <int NT>
__device__ __forceinline__ void gather_role(const f16* __restrict__ A,
                                            const f16* __restrict__ B,
                                            const int* __restrict__ labels,
                                            float* __restrict__ lp_lab,
                                            int n, int rbase, int lane) {
    __builtin_amdgcn_s_setprio(2);
    int lm = lane & 15, hi = lane >> 4;
    int cls0 = (lm == 0) ? 0 : labels[n * SS + lm - 1];       // j = lm
    int cls1 = (lm >= 15) ? 0 : labels[n * SS + lm + 15];     // j = 16+lm
    const f16* pb0 = B + (size_t)cls0 * DD + hi * 8;
    const f16* pb1 = B + (size_t)cls1 * DD + hi * 8;
    // chunk order {0,3} b0 {1,2} b1: both chains start after one barrier.
    gather_chunk<NT>(pb0, pb1, A, lp_lab, n, 0, rbase, lane);
    gather_chunk<NT>(pb0, pb1, A, lp_lab, n, 3, rbase, lane);
    __syncthreads();                     // b0: chunks 0,3 published
    gather_chunk<NT>(pb0, pb1, A, lp_lab, n, 1, rbase, lane);
    gather_chunk<NT>(pb0, pb1, A, lp_lab, n, 2, rbase, lane);
    __builtin_amdgcn_s_setprio(0);
    __syncthreads();                     // b1: chunks 1,2 published
    __syncthreads();                     // b2 (match chain waves)
}

// ---- mega (320-thread blocks): blocks 0..31 = {w0 fwd chain, w1 bwd chain,
//      w2-4 gather NT=3/3/2}; blocks 32..1439 = gemm+sumexp on waves 0-3
//      (16KB LDS, XOR swizzle, XCD-aware bm grouping), wave 4 barrier-match. ----
__global__ __launch_bounds__(320) void mega_kernel(const f16* __restrict__ A,
                                                   const f16* __restrict__ B,
                                                   const int* __restrict__ labels,
                                                   const int* __restrict__ in_lens,
                                                   const int* __restrict__ lab_lens,
                                                   float* __restrict__ sumexp,
                                                   float* __restrict__ lp_lab,
                                                   double* __restrict__ part) {
    __shared__ __align__(16) f16 sm[8192];   // 16 KB (gemm tiles | gc dot buf)
    int bx = blockIdx.x;
    int tid = threadIdx.x;
    int w = tid >> 6, lane = tid & 63;
    int lm = lane & 15, hi = lane >> 4;
    int sw = (lm >> 1) & 3;                // fragment-read channel swizzle

    if (bx >= MEGA_GC) {
        if (w == 4) {                      // barrier-match wave (gemm blocks)
            for (int i = 0; i < 32; ++i) __syncthreads();
            return;
        }
        // ================= GEMM section (identical since R19) ===============
        int j = bx - MEGA_GC;
        int x = j & 7, rr = j >> 3;            // XCD-aware: per-XCD bm range
        int bm = x * 16 + (rr & 15);
        int bn = rr >> 4;                      // [0,11)
        int wm = w >> 1, wn = w & 1;           // 2x2 wave grid -> 64x64 per wave
        f32x4 acc[4][4];
        f32x4 zero = {0.f, 0.f, 0.f, 0.f};
        #pragma unroll
        for (int i = 0; i < 4; ++i)
            #pragma unroll
            for (int jj = 0; jj < 4; ++jj) acc[i][jj] = zero;

        for (int kb = 0; kb < 16; ++kb) {      // K=512, BK=32 (one MFMA K-step)
            #pragma unroll
            for (int p = 0; p < 2; ++p) {
                int s = p * 256 + tid;         // tid < 256 here (waves 0-3)
                int row = s >> 2;
                int ch = (s & 3) ^ ((row >> 1) & 3);   // swizzled source channel
                const f16* ga = A + (size_t)(bm * 128 + row) * DD + kb * 32 + ch * 8;
                const f16* gb = B + (size_t)(bn * 128 + row) * DD + kb * 32 + ch * 8;
                __builtin_amdgcn_global_load_lds((as1_void_ptr)ga,
                    (as3_void_ptr)&sm[(p * 256 + w * 64) * 8], 16, 0, 0);
                __builtin_amdgcn_global_load_lds((as1_void_ptr)gb,
                    (as3_void_ptr)&sm[4096 + (p * 256 + w * 64) * 8], 16, 0, 0);
            }
            __syncthreads();
            f16x8 af[4], bf[4];
            #pragma unroll
            for (int i = 0; i < 4; ++i)
                af[i] = *(const f16x8*)&sm[(wm * 64 + i * 16 + lm) * 32 + (hi ^ sw) * 8];
            #pragma unroll
            for (int jj = 0; jj < 4; ++jj)
                bf[jj] = *(const f16x8*)&sm[4096 + (wn * 64 + jj * 16 + lm) * 32 + (hi ^ sw) * 8];
            #pragma unroll
            for (int i = 0; i < 4; ++i)
                #pragma unroll
                for (int jj = 0; jj < 4; ++jj)
                    acc[i][jj] = __builtin_amdgcn_mfma_f32_16x16x32_f16(af[i], bf[jj], acc[i][jj], 0, 0, 0);
            __syncthreads();
        }
        #pragma unroll
        for (int i = 0; i < 4; ++i) {
            float rs[4] = {0.f, 0.f, 0.f, 0.f};
            #pragma unroll
            for (int jj = 0; jj < 4; ++jj) {
                int c = bn * 128 + wn * 64 + jj * 16 + lm;   // C/D: col = lane&15
                bool ok = (c < CC);
                #pragma unroll
                for (int r = 0; r < 4; ++r)
                    rs[r] += ok ? fexp2(acc[i][jj][r] * (NORM_SCALE * LOG2E)) : 0.f;
            }
            #pragma unroll
            for (int off = 1; off < 16; off <<= 1) {
                #pragma unroll
                for (int r = 0; r < 4; ++r) rs[r] += __shfl_xor(rs[r], off);
            }
            if (lm == 0) {
                int rowb = bm * 128 + wm * 64 + i * 16 + hi * 4;
                #pragma unroll
                for (int r = 0; r < 4; ++r) atomicAdd(&sumexp[rowb + r], rs[r]);
            }
        }
        return;
    }

    // ================= gather + fwd/bwd ctc section (block n = bx) ==========
    int n = bx;
    if (w >= 2) {
        if (w < 4) gather_role<3>(A, B, labels, lp_lab, n, (w - 2) * 48, lane);
        else       gather_role<2>(A, B, labels, lp_lab, n, 96, lane);
        return;
    }

    int s = lane;            // 64 lanes; states 0..60 valid
    bool valid = s < LL;
    int ext = (valid && (s & 1)) ? labels[n * SS + (s >> 1)] : 0;
    int jmap = (valid && (s & 1)) ? ((s >> 1) + 1) : 0;   // state -> class slot
    int Tin = in_lens[n];    // wave-uniform; in [481,512]
    const float* lpr = lp_lab + ((size_t)n * 31 + jmap) * TT;
    double* vb = (double*)sm;                // cross-wave dot buffer

    if (w == 0) {
        // ---------------- forward: alpha over t = 0..255 --------------------
        int ext2 = __shfl_up(ext, 2);
        double skipd = ((s >= 2) && valid && (ext != ext2)) ? 1.0 : 0.0;
        double sk1 = dpp_sr1_zero64(skipd);
        double sk2 = dpp_sr1_zero64(sk1);
        double kk2 = skipd * sk2;
        const float4* g4 = (const float4*)lpr;
        double beta = 0.0;
        int Mif = 0;

        auto stepL = [&](float lp) {
            double P = (double)fexp2(lp);
            double b1 = dpp_sr1_zero64(beta);
            double b2 = dpp_sr1_zero64(b1);
            beta = (beta + b1 + b2 * skipd) * P;
        };
        auto step2 = [&](float lp1, float lp2) {
            double q  = (double)fexp2(lp1);
            double P2 = (double)fexp2(lp2);
            double q1 = dpp_sr1_zero64(q);
            double q2 = dpp_sr1_zero64(q1);
            double c1 = q + q1;
            double c2 = fma(skipd, q + q2, q1);
            double c3 = fma(sk1, q1, skipd * q2);
            double c4 = kk2 * q2;
            double b1 = dpp_sr1_zero64(beta);
            double b2 = dpp_sr1_zero64(b1);
            double b3 = dpp_sr1_zero64(b2);
            double b4 = dpp_sr1_zero64(b3);
            double u = fma(c1, b1, q * beta);
            double v2 = fma(c3, b3, c2 * b2);
            beta = (u + fma(c4, b4, v2)) * P2;
        };

        __builtin_amdgcn_s_setprio(3);
        __syncthreads();                     // b0: chunks 0,3 ready
        float4 q0 = g4[0];
        beta = (s <= 1) ? (double)fexp2(q0.x) : 0.0;
        stepL(q0.y); stepL(q0.z); stepL(q0.w);   // t = 1..3
        renorm_d(beta, Mif);
        float4 cu = g4[1];
        for (int gi = 1; gi <= 31; ++gi) {       // t = 4..127
            float4 nx = g4[gi < 31 ? gi + 1 : 31];
            step2(cu.x, cu.y); step2(cu.z, cu.w);
            if (gi & 1) renorm_d(beta, Mif);
            cu = nx;
        }
        __syncthreads();                     // b1: chunks 1,2 ready
        cu = g4[32];
        for (int gi = 32; gi <= 63; ++gi) {      // t = 128..255
            float4 nx = g4[gi < 63 ? gi + 1 : 63];
            step2(cu.x, cu.y); step2(cu.z, cu.w);
            if (gi & 1) renorm_d(beta, Mif);
            cu = nx;
        }
        renorm_d(beta, Mif);
        __syncthreads();                     // b2: bwd vector published
        __builtin_amdgcn_s_setprio(0);
        double pr = beta * vb[s];            // v[s>=LL] == 0: garbage excluded
        #pragma unroll
        for (int off = 32; off; off >>= 1) pr += __shfl_xor(pr, off);
        if (s == 0) {
            long long bb = __double_as_longlong(pr);
            int e = (int)(bb >> 52) - 1023;
            double mant = __longlong_as_double((bb & 0xFFFFFFFFFFFFFLL) | (1023LL << 52));
            part[n] = (double)flog2((float)mant) + (double)(e + Mif) + vb[64];
        }
        return;
    }

    // ---------------- backward: v^T <- v^T A_t, t = Tin-1 .. 256 ------------
    {
        float maskf = valid ? 1.f : 0.f;     // p=0 outside states: no garbage
        int extd1 = __shfl_down(ext, 1);
        int extd2 = __shfl_down(ext, 2);
        int extd3 = __shfl_down(ext, 3);
        int extd4 = __shfl_down(ext, 4);
        double k2d = ((s + 2) < LL && extd2 != ext)   ? 1.0 : 0.0;  // k[s+2]
        double k3d = ((s + 3) < LL && extd3 != extd1) ? 1.0 : 0.0;  // k[s+3]
        double k4d = ((s + 4) < LL && extd4 != extd2) ? 1.0 : 0.0;  // k[s+4]
        int Ln = 2 * lab_lens[n] + 1;
        double v = (s == Ln - 1 || s == Ln - 2) ? 1.0 : 0.0;
        int Mib = 0;

        // v'' = c0*v + c1*v[s+1] + c2*v[s+2] + c3*v[s+3] + c4*v[s+4]
        // (A_t then A_{t-1}; p=2^lp_t, r=2^lp_{t-1}; verified on-HW in R20)
        auto step2b = [&](float lph, float lpl) {
            float p  = maskf * fexp2(lph);
            float rr = maskf * fexp2(lpl);
            float p1 = dpp_sl1_zero32(p);
            float p2 = dpp_sl1_zero32(p1);
            float p3 = dpp_sl1_zero32(p2);
            float p4 = dpp_sl1_zero32(p3);
            float r1 = dpp_sl1_zero32(rr);
            float r2 = dpp_sl1_zero32(r1);
            double rd = (double)rr, rd1 = (double)r1, rd2 = (double)r2;
            double c0 = (double)p * rd;
            double c1 = (double)p1 * (rd + rd1);
            double c2 = (double)p2 * fma(k2d, rd + rd2, rd1);
            double c3 = (double)p3 * fma(k3d, rd1, k2d * rd2);
            double c4 = (double)p4 * (k2d * rd2) * k4d;
            double v1 = dpp_sl1_zero64(v);
            double v2 = dpp_sl1_zero64(v1);
            double v3 = dpp_sl1_zero64(v2);
            double v4 = dpp_sl1_zero64(v3);
            double u  = fma(c1, v1, c0 * v);
            double t2 = fma(c3, v3, c2 * v2);
            v = u + fma(c4, v4, t2);
        };
        auto step1b = [&](float lph) {       // v' = u + u[s+1] + k[s+2]u[s+2]
            float p = maskf * fexp2(lph);
            double u  = (double)p * v;
            double u1 = dpp_sl1_zero64(u);
            double u2 = dpp_sl1_zero64(u1);
            v = u + u1 + k2d * u2;
        };

        __builtin_amdgcn_s_setprio(3);
        __syncthreads();                     // b0: chunk 3 (t>=384) ready
        int tc = Tin - 1;
        float h0 = lpr[tc], l0 = lpr[tc - 1];
        int rnc = 0;
        while (tc >= 385) {                  // phase A: down to t=384
            int tn = tc - 2;
            float h1 = (tn >= 384) ? lpr[tn] : 0.f;       // stay in chunk 3
            float l1 = (tn >= 385) ? lpr[tn - 1] : 0.f;
            step2b(h0, l0);
            if (((++rnc) & 3) == 0) renorm_d(v, Mib);
            tc = tn; h0 = h1; l0 = l1;
        }
        if (tc == 384) { step1b(h0); tc = 383; }
        renorm_d(v, Mib);
        __syncthreads();                     // b1: chunk 2 (t in [256,384)) ready
        tc = 383;
        h0 = lpr[tc]; l0 = lpr[tc - 1];
        rnc = 0;
        while (tc >= 257) {                  // phase B: down to t=256
            int tn = tc - 2;
            float h1 = (tn >= 257) ? lpr[tn] : 0.f;
            float l1 = (tn >= 257) ? lpr[tn - 1] : 0.f;
            step2b(h0, l0);
            if (((++rnc) & 3) == 0) renorm_d(v, Mib);
            tc = tn; h0 = h1; l0 = l1;
        }
        renorm_d(v, Mib);
        vb[s] = v;
        if (s == 0) vb[64] = (double)Mib;
        __builtin_amdgcn_s_setprio(0);
        __syncthreads();                     // b2: publish v + Mi_b
        return;
    }
}

// ---- final: Msum per n (f64, fixed order) + nll + deterministic sum ----
__global__ __launch_bounds__(1024) void final_kernel(const float* __restrict__ sumexp,
                                                     const int* __restrict__ in_lens,
                                                     const double* __restrict__ part,
                                                     float* __restrict__ out) {
    int tid = threadIdx.x;
    int v = tid >> 6, lane = tid & 63;     // 16 waves, 2 samples each
    __shared__ float nl[NN];
    #pragma unroll
    for (int k = 0; k < 2; ++k) {
        int n = v * 2 + k;
        int Tin = in_lens[n];
        double ms = 0.0;
        for (int t = lane; t < Tin; t += 64)
            ms += (double)flog2(sumexp[(size_t)t * NN + n]);
        #pragma unroll
        for (int off = 32; off; off >>= 1) ms += __shfl_xor(ms, off);
        if (lane == 0) nl[n] = (float)(-(part[n] - ms) * LN2);
    }
    __syncthreads();
    if (tid == 0) {
        float t = 0.f;
        for (int i = 0; i < NN; ++i) t += nl[i];
        out[0] = t;
    }
}

extern "C" void kernel_launch(void* const* d_in, const int* in_sizes, int n_in,
                              void* d_out, int out_size, void* d_ws, size_t ws_size,
                              hipStream_t stream) {
    const float* feats        = (const float*)d_in[0];
    const float* W            = (const float*)d_in[1];
    const int*   labeling     = (const int*)d_in[2];
    const int*   logit_lgts   = (const int*)d_in[3];
    const int*   labeling_lgts= (const int*)d_in[4];
    float* out = (float*)d_out;
    char* ws = (char*)d_ws;

    size_t off = 0;
    f16*   wt     = (f16*)(ws + off);   off += (size_t)CP * DD * 2;        // 1.44 MB
    f16*   fn     = (f16*)(ws + off);   off += (size_t)TT * NN * DD * 2;   // 16.8 MB
    float* sumexp = (float*)(ws + off); off += (size_t)TT * NN * 4;        // 64 KB
    float* lp_lab = (float*)(ws + off); off += (size_t)NN * 31 * TT * 4;   // 2.0 MB
    double* part  = (double*)(ws + off); off += NN * 8;

    prep_kernel<<<PREP_WBLK + PREP_ZBLK + PREP_FBLK, 256, 0, stream>>>(
        W, feats, wt, fn, sumexp);
    mega_kernel<<<MEGA_BLK, 320, 0, stream>>>(fn, wt, labeling, logit_lgts,
                                              labeling_lgts, sumexp, lp_lab, part);
    final_kernel<<<1, 1024, 0, stream>>>(sumexp, logit_lgts, part, out);

    (void)in_sizes; (void)n_in; (void)out_size; (void)ws_size;
}